// Round 14
// baseline (543.551 us; speedup 1.0000x reference)
//
#include <hip/hip_runtime.h>

#define NN 50000
#define EE 800000

using short8v = __attribute__((ext_vector_type(8))) short;
using f32x4 = __attribute__((ext_vector_type(4))) float;

// ---------------- bf16 helpers ----------------
__device__ inline unsigned int bf_pack(float lo, float hi) {
  unsigned int a = __float_as_uint(lo);
  a += 0x7FFFu + ((a >> 16) & 1u);
  unsigned int b = __float_as_uint(hi);
  b += 0x7FFFu + ((b >> 16) & 1u);
  return (a >> 16) | ((b >> 16) << 16);
}
__device__ inline void bf_dec8(uint4 v, float* f) {
  f[0] = __uint_as_float(v.x << 16); f[1] = __uint_as_float(v.x & 0xFFFF0000u);
  f[2] = __uint_as_float(v.y << 16); f[3] = __uint_as_float(v.y & 0xFFFF0000u);
  f[4] = __uint_as_float(v.z << 16); f[5] = __uint_as_float(v.z & 0xFFFF0000u);
  f[6] = __uint_as_float(v.w << 16); f[7] = __uint_as_float(v.w & 0xFFFF0000u);
}
__device__ inline float lrelu(float v) { return v >= 0.f ? v : 0.2f * v; }

// truncation split of 8 fp32 into bf16 hi + bf16 lo (packed as uint4 each).
__device__ inline void split_pack8(const float* v, uint4& h, uint4& l) {
  unsigned int hb[8], lb[8];
  #pragma unroll
  for (int j = 0; j < 8; j++) {
    unsigned int b = __float_as_uint(v[j]);
    hb[j] = b & 0xFFFF0000u;
    float r = v[j] - __uint_as_float(hb[j]);
    lb[j] = __float_as_uint(r) & 0xFFFF0000u;
  }
  h.x = (hb[0] >> 16) | hb[1]; h.y = (hb[2] >> 16) | hb[3];
  h.z = (hb[4] >> 16) | hb[5]; h.w = (hb[6] >> 16) | hb[7];
  l.x = (lb[0] >> 16) | lb[1]; l.y = (lb[2] >> 16) | lb[3];
  l.z = (lb[4] >> 16) | lb[5]; l.w = (lb[6] >> 16) | lb[7];
}

#define SC_BPR 256

// ======== fold a_l/a_r through weights (must precede front_k: xdot uses wl1) ==
__global__ __launch_bounds__(256) void fold_k(
    const float* __restrict__ W1, const float* __restrict__ al1, const float* __restrict__ ar1,
    const float* __restrict__ W2, const float* __restrict__ al2, const float* __restrict__ ar2,
    const float* __restrict__ Wm, const float* __restrict__ alm, const float* __restrict__ arm,
    float* __restrict__ wl1, float* __restrict__ wr1,
    float* __restrict__ wl2, float* __restrict__ wr2,
    float* __restrict__ wlm, float* __restrict__ wrm) {
  int t = blockIdx.x * 256 + threadIdx.x;
  if (t < 512) {
    int lr = t >> 8, e = (t >> 7) & 1, k = t & 127;
    const float* a = (lr ? ar1 : al1) + e * 128;
    const float* w = W1 + ((size_t)e * 128 + k) * 128;
    float s = 0.f;
    for (int f = 0; f < 128; f++) s += w[f] * a[f];
    (lr ? wr1 : wl1)[e * 128 + k] = s;
  } else if (t < 1024) {
    int u = t - 512;
    int lr = u >> 8, e = (u >> 7) & 1, k = u & 127;
    const float* a = (lr ? ar2 : al2) + e * 64;
    const float* w = W2 + ((size_t)e * 128 + k) * 64;
    float s = 0.f;
    for (int f = 0; f < 64; f++) s += w[f] * a[f];
    (lr ? wr2 : wl2)[e * 128 + k] = s;
  } else if (t < 2048) {
    int u = t - 1024;
    int lr = u >> 9, e = (u >> 8) & 1, h = (u >> 6) & 3, k = u & 63;
    const float* a = (lr ? arm : alm) + (e * 4 + h) * 64;
    const float* w = Wm + ((size_t)e * 64 + k) * 256 + h * 64;
    float s = 0.f;
    for (int f = 0; f < 64; f++) s += w[f] * a[f];
    (lr ? wrm : wlm)[(e * 4 + h) * 64 + k] = s;
  }
}

// ===== front_k: grid-union of {passA (label-private atomic rank gen), xdot,
// wtrans}. blocks [0,1563): passA | [1563,4688): xdot | [4688,5008): wtrans.
// passA uses partition label = blockIdx&7 (== XCD under round-robin dispatch;
// correctness is label-agnostic, only locality depends on the mapping).
// Atomics go to the label's PRIVATE counter copy -> if mapping holds, all
// writers of a line sit on one XCD and the atomic is L2-local.
// rel[i] = (lab<<16) | within-copy-rank (per-copy degree << 65536).
__global__ __launch_bounds__(256) void front_k(
    const int* __restrict__ dst0, const int* __restrict__ dst1,
    int* __restrict__ deg_p, int* __restrict__ rel,
    const float* __restrict__ x, const float* __restrict__ wl,
    const float* __restrict__ wr, unsigned int* __restrict__ xb,
    float* __restrict__ el, float* __restrict__ er,
    const float* __restrict__ W1, const float* __restrict__ W2,
    const float* __restrict__ Wm,
    unsigned short* __restrict__ w1h, unsigned short* __restrict__ w1l,
    unsigned short* __restrict__ w2h, unsigned short* __restrict__ w2l,
    unsigned short* __restrict__ wmh, unsigned short* __restrict__ wml) {
  const int blk = blockIdx.x;
  if (blk < 1563) {
    const int lab = blk & 7;
    int* dg = deg_p + lab * 100000;
    int i = blk * 256 + threadIdx.x;
    if (i < 200000) {
      int4 d = ((const int4*)dst0)[i];
      int4 r;
      r.x = (lab << 16) | atomicAdd(&dg[d.x], 1);
      r.y = (lab << 16) | atomicAdd(&dg[d.y], 1);
      r.z = (lab << 16) | atomicAdd(&dg[d.z], 1);
      r.w = (lab << 16) | atomicAdd(&dg[d.w], 1);
      ((int4*)rel)[i] = r;
    } else if (i < 400000) {
      int4 d = ((const int4*)dst1)[i - 200000];
      int* dg1 = dg + 50000;
      int4 r;
      r.x = (lab << 16) | atomicAdd(&dg1[d.x], 1);
      r.y = (lab << 16) | atomicAdd(&dg1[d.y], 1);
      r.z = (lab << 16) | atomicAdd(&dg1[d.z], 1);
      r.w = (lab << 16) | atomicAdd(&dg1[d.w], 1);
      ((int4*)(rel + EE))[i - 200000] = r;
    }
  } else if (blk < 4688) {
    int bx = blk - 1563;
    int n = bx * 16 + (threadIdx.x >> 4);
    int lane = threadIdx.x & 15;
    if (n >= NN) return;
    float p[4] = {0.f, 0.f, 0.f, 0.f};
    #pragma unroll
    for (int i = 0; i < 2; i++) {
      int c = (lane + i * 16) * 4;
      float4 xv = *(const float4*)(x + (size_t)n * 128 + c);
      uint2 o;
      o.x = bf_pack(xv.x, xv.y);
      o.y = bf_pack(xv.z, xv.w);
      *(uint2*)(xb + (size_t)n * 64 + c / 2) = o;
      #pragma unroll
      for (int e = 0; e < 2; e++) {
        float4 a = *(const float4*)(wl + e * 128 + c);
        float4 b = *(const float4*)(wr + e * 128 + c);
        p[e*2+0] += xv.x*a.x + xv.y*a.y + xv.z*a.z + xv.w*a.w;
        p[e*2+1] += xv.x*b.x + xv.y*b.y + xv.z*b.z + xv.w*b.w;
      }
    }
    #pragma unroll
    for (int off = 1; off < 16; off <<= 1) {
      #pragma unroll
      for (int i = 0; i < 4; i++) p[i] += __shfl_xor(p[i], off);
    }
    if (lane == 0) {
      el[n] = p[0]; er[n] = p[1];
      el[NN + n] = p[2]; er[NN + n] = p[3];
    }
  } else {
    int t = (blk - 4688) * 256 + threadIdx.x;
    float v; unsigned short *ph, *pl; int oi;
    if (t < 32768) {                       // W1: K=128 (KG=16), N=128
      int j = t & 7, n = (t >> 3) & 127, kg = (t >> 10) & 15, e = t >> 14;
      v = W1[((size_t)(e * 128 + kg * 8 + j)) * 128 + n];
      ph = w1h; pl = w1l; oi = t;
    } else if (t < 49152) {                // W2: K=128 (KG=16), N=64
      int i = t - 32768;
      int j = i & 7, n = (i >> 3) & 63, kg = (i >> 9) & 15, e = i >> 13;
      v = W2[((size_t)(e * 128 + kg * 8 + j)) * 64 + n];
      ph = w2h; pl = w2l; oi = i;
    } else if (t < 81920) {                // Wm: K=64 (KG=8), N=256
      int i = t - 49152;
      int j = i & 7, n = (i >> 3) & 255, kg = (i >> 11) & 7, e = i >> 14;
      v = Wm[((size_t)(e * 64 + kg * 8 + j)) * 256 + n];
      ph = wmh; pl = wml; oi = i;
    } else return;
    unsigned int b = __float_as_uint(v);
    unsigned int hb = b & 0xFFFF0000u;
    float r = v - __uint_as_float(hb);
    unsigned int lb = __float_as_uint(r);
    ph[oi] = (unsigned short)(hb >> 16);
    pl[oi] = (unsigned short)(lb >> 16);
  }
}

// combine label-private counts -> totals (for scans) + in-place exclusive
// per-label bases (for passB).
__global__ __launch_bounds__(256) void combine_k(
    int* __restrict__ deg_p, int* __restrict__ deg) {
  int t = blockIdx.x * 256 + threadIdx.x;   // over 2*50000 (e-major)
  if (t >= 100000) return;
  int s = 0;
  int b[8];
  #pragma unroll
  for (int lab = 0; lab < 8; lab++) {
    b[lab] = s;
    s += deg_p[lab * 100000 + t];
  }
  deg[t] = s;
  #pragma unroll
  for (int lab = 0; lab < 8; lab++)
    deg_p[lab * 100000 + t] = b[lab];
}

__global__ __launch_bounds__(512) void scan1_k(const int* __restrict__ deg,
                                               int* __restrict__ inc,
                                               int* __restrict__ bsum) {
  __shared__ int s[512];
  int e = blockIdx.y;
  int t = threadIdx.x, i = blockIdx.x * 512 + t;
  int v = (i < NN) ? deg[e * 50000 + i] : 0;
  s[t] = v; __syncthreads();
  #pragma unroll
  for (int off = 1; off < 512; off <<= 1) {
    int u = (t >= off) ? s[t - off] : 0;
    __syncthreads();
    s[t] += u;
    __syncthreads();
  }
  if (i < NN) inc[e * 50000 + i] = s[t];
  if (t == 511) bsum[e * 128 + blockIdx.x] = s[511];
}

__global__ __launch_bounds__(128) void scan2_k(int* __restrict__ bsum, int nb) {
  __shared__ int s[128];
  int e = blockIdx.x;
  int t = threadIdx.x;
  int v = (t < nb) ? bsum[e * 128 + t] : 0;
  s[t] = v; __syncthreads();
  #pragma unroll
  for (int off = 1; off < 128; off <<= 1) {
    int u = (t >= off) ? s[t - off] : 0;
    __syncthreads();
    s[t] += u;
    __syncthreads();
  }
  if (t < nb) bsum[e * 128 + t] = s[t] - v;
}

__global__ __launch_bounds__(256) void scan3_k(const int* __restrict__ deg,
                                               const int* __restrict__ inc,
                                               const int* __restrict__ bsum,
                                               int* __restrict__ rowptr) {
  int e = blockIdx.y;
  int i = blockIdx.x * 256 + threadIdx.x;
  if (i < NN) {
    rowptr[e * 50001 + i] =
        inc[e * 50000 + i] - deg[e * 50000 + i] + bsum[e * 128 + (i >> 9)];
  }
  if (i == NN) rowptr[e * 50001 + NN] = EE;
}

// passB: atomic-free placement. XCD-partitioned by dst range (write locality);
// rowptr slice in LDS; per-edge final position = rowptr + base[lab] + rank.
__global__ __launch_bounds__(256) void passB_k(
    const int* __restrict__ src0, const int* __restrict__ dst0,
    const int* __restrict__ src1, const int* __restrict__ dst1,
    const int* __restrict__ rel, const int* __restrict__ rowptr,
    const int* __restrict__ deg_p, int* __restrict__ csr_src) {
  __shared__ int rp_s[2][6250];
  const int range = blockIdx.x & 7;
  const int bpr = blockIdx.x >> 3;
  const int lo = range * 6250;
  const int hi = lo + 6250;
  for (int k = threadIdx.x; k < 6250; k += 256) {
    rp_s[0][k] = rowptr[lo + k];
    rp_s[1][k] = rowptr[50001 + lo + k];
  }
  __syncthreads();
  #pragma unroll
  for (int e = 0; e < 2; e++) {
    const int4* ds4 = (const int4*)(e ? dst1 : dst0);
    const int* ss = e ? src1 : src0;
    const int4* rl4 = (const int4*)(rel + (size_t)e * EE);
    const int* rps = rp_s[e];
    const int* bp = deg_p + e * 50000;
    int* outp = csr_src + (size_t)e * EE;
    for (int i = bpr * 256 + threadIdx.x; i < EE / 4; i += SC_BPR * 256) {
      int4 d = ds4[i];
      int4 rl = rl4[i];
      int b = i * 4;
      if (d.x >= lo && d.x < hi) {
        int lab = ((unsigned)rl.x) >> 16, rk = rl.x & 0xFFFF;
        outp[rps[d.x - lo] + bp[lab * 100000 + d.x] + rk] = ss[b];
      }
      if (d.y >= lo && d.y < hi) {
        int lab = ((unsigned)rl.y) >> 16, rk = rl.y & 0xFFFF;
        outp[rps[d.y - lo] + bp[lab * 100000 + d.y] + rk] = ss[b + 1];
      }
      if (d.z >= lo && d.z < hi) {
        int lab = ((unsigned)rl.z) >> 16, rk = rl.z & 0xFFFF;
        outp[rps[d.z - lo] + bp[lab * 100000 + d.z] + rk] = ss[b + 2];
      }
      if (d.w >= lo && d.w < hi) {
        int lab = ((unsigned)rl.w) >> 16, rk = rl.w & 0xFFFF;
        outp[rps[d.w - lo] + bp[lab * 100000 + d.w] + rk] = ss[b + 3];
      }
    }
  }
}

// ===== layer1: one-pass alpha + gather of bf16 x; etype = blockIdx.y =====
// Loads issued in static batches of 8 (named registers).
__global__ __launch_bounds__(256) void agg_x_f(
    const int* __restrict__ rowptr, const int* __restrict__ csr_src,
    const float* __restrict__ el, const float* __restrict__ er,
    const uint4* __restrict__ xb, float* __restrict__ u1) {
  int d = blockIdx.x * 16 + (threadIdx.x >> 4);
  int lane = threadIdx.x & 15;
  if (d >= NN) return;
  const int e = blockIdx.y;
  const int* rp = rowptr + e * 50001;
  const int* cs = csr_src + (size_t)e * EE;
  const float* elp = el + (size_t)e * NN;
  float erd = er[(size_t)e * NN + d];
  int j0 = rp[d], j1 = rp[d + 1];
  float sm = 0.f;
  float acc[8] = {};
  for (int j = j0; j < j1; j += 16) {
    int cnt = j1 - j; if (cnt > 16) cnt = 16;
    int jj = j + (lane < cnt ? lane : 0);
    int sl = cs[jj];
    float alv = (lane < cnt) ? __expf(lrelu(elp[sl] + erd)) : 0.f;
    sm += alv;
    {
      int sv[8]; float av[8]; uint4 xv[8];
      #pragma unroll
      for (int k = 0; k < 8; k++) {
        sv[k] = __shfl(sl, k, 16);
        av[k] = __shfl(alv, k, 16);
      }
      #pragma unroll
      for (int k = 0; k < 8; k++) xv[k] = xb[(size_t)sv[k] * 16 + lane];
      #pragma unroll
      for (int k = 0; k < 8; k++) {
        float f[8]; bf_dec8(xv[k], f);
        #pragma unroll
        for (int c = 0; c < 8; c++) acc[c] += av[k] * f[c];
      }
    }
    if (cnt > 8) {
      int sv[8]; float av[8]; uint4 xv[8];
      #pragma unroll
      for (int k = 0; k < 8; k++) {
        sv[k] = __shfl(sl, 8 + k, 16);
        av[k] = __shfl(alv, 8 + k, 16);
      }
      #pragma unroll
      for (int k = 0; k < 8; k++) xv[k] = xb[(size_t)sv[k] * 16 + lane];
      #pragma unroll
      for (int k = 0; k < 8; k++) {
        float f[8]; bf_dec8(xv[k], f);
        #pragma unroll
        for (int c = 0; c < 8; c++) acc[c] += av[k] * f[c];
      }
    }
  }
  #pragma unroll
  for (int off = 1; off < 16; off <<= 1) sm += __shfl_xor(sm, off, 16);
  float inv = 1.f / fmaxf(sm, 1e-9f);
  float* up = u1 + ((size_t)e * NN + d) * 128 + lane * 8;
  *(float4*)up       = make_float4(acc[0]*inv, acc[1]*inv, acc[2]*inv, acc[3]*inv);
  *(float4*)(up + 4) = make_float4(acc[4]*inv, acc[5]*inv, acc[6]*inv, acc[7]*inv);
}

// ===== fused layer1-GEMM + layer2 dots + layer2-GEMM (h1 stays in LDS) =====
// BM=64: LDS 33.8 KB -> 4 blocks/CU, 782 blocks. Each wave owns 16 rows.
__global__ __launch_bounds__(256) void layer12_k(
    const float* __restrict__ u1, const unsigned short* __restrict__ w1h,
    const unsigned short* __restrict__ w1l, const float* __restrict__ b1,
    const unsigned short* __restrict__ w2h, const unsigned short* __restrict__ w2l,
    const float* __restrict__ wl2, const float* __restrict__ wr2,
    unsigned int* __restrict__ Zb, float* __restrict__ el,
    float* __restrict__ er) {
  __shared__ float smem[64 * 132];            // 33.8 KB; staging aliased
  uint4* AsH = (uint4*)smem;                  // 256 uint4 = 4 KB
  uint4* AsL = AsH + 256;                     // 4 KB
  float* Hs = smem;
  const int tid = threadIdx.x;
  const int row0 = blockIdx.x * 64;
  const int wv = tid >> 6, lane = tid & 63;
  const int l15 = lane & 15, lg = lane >> 4;
  const uint4* b1h4 = (const uint4*)w1h;
  const uint4* b1l4 = (const uint4*)w1l;
  const uint4* b2h4 = (const uint4*)w2h;
  const uint4* b2l4 = (const uint4*)w2l;

  // ---------- stage 1: h1 = 0.5*(u1[0]@W1[0]+u1[1]@W1[1]) + bias ----------
  f32x4 acc[8] = {};
  for (int e = 0; e < 2; e++) {
    const float* Ap = u1 + (size_t)e * NN * 128;
    for (int k0 = 0; k0 < 128; k0 += 32) {
      {
        int r = tid & 63, kgl = tid >> 6;    // 64 rows x 4 kgroups
        int rr = row0 + r; if (rr >= NN) rr = NN - 1;
        const float* ap = Ap + (size_t)rr * 128 + k0 + kgl * 8;
        float4 a0 = *(const float4*)ap;
        float4 a1 = *(const float4*)(ap + 4);
        float v[8] = {a0.x, a0.y, a0.z, a0.w, a1.x, a1.y, a1.z, a1.w};
        uint4 hh, ll;
        split_pack8(v, hh, ll);
        AsH[kgl * 64 + r] = hh;
        AsL[kgl * 64 + r] = ll;
      }
      __syncthreads();
      int slot = lg * 64 + wv * 16 + l15;
      short8v ah = *reinterpret_cast<const short8v*>(&AsH[slot]);
      short8v al = *reinterpret_cast<const short8v*>(&AsL[slot]);
      int kgb = e * 16 + (k0 >> 3) + lg;
      #pragma unroll
      for (int nf = 0; nf < 8; nf++) {
        int bslot = kgb * 128 + nf * 16 + l15;
        short8v bh = *reinterpret_cast<const short8v*>(&b1h4[bslot]);
        short8v bl = *reinterpret_cast<const short8v*>(&b1l4[bslot]);
        acc[nf] = __builtin_amdgcn_mfma_f32_16x16x32_bf16(ah, bh, acc[nf], 0, 0, 0);
        acc[nf] = __builtin_amdgcn_mfma_f32_16x16x32_bf16(al, bh, acc[nf], 0, 0, 0);
        acc[nf] = __builtin_amdgcn_mfma_f32_16x16x32_bf16(ah, bl, acc[nf], 0, 0, 0);
      }
      __syncthreads();
    }
  }
  // ---------- h1 -> LDS (f32, pitch 132) ----------
  #pragma unroll
  for (int nf = 0; nf < 8; nf++) {
    int col = nf * 16 + l15;
    float bb = 0.5f * (b1[col] + b1[128 + col]);
    #pragma unroll
    for (int reg = 0; reg < 4; reg++) {
      int rloc = wv * 16 + lg * 4 + reg;
      Hs[rloc * 132 + col] = 0.5f * acc[nf][reg] + bb;
    }
  }
  __syncthreads();
  // ---------- layer2 el/er dots (4 threads/row, interleaved cols) ----------
  {
    int r = tid >> 2, q = tid & 3;
    int grow = row0 + r;
    const float* hrow = Hs + r * 132;
    float p0 = 0.f, p1 = 0.f, p2 = 0.f, p3 = 0.f;
    #pragma unroll 8
    for (int c = 0; c < 32; c++) {
      int k = q + c * 4;
      float hv = hrow[k];
      p0 += hv * wl2[k];       p1 += hv * wr2[k];
      p2 += hv * wl2[128 + k]; p3 += hv * wr2[128 + k];
    }
    p0 += __shfl_xor(p0, 1); p0 += __shfl_xor(p0, 2);
    p1 += __shfl_xor(p1, 1); p1 += __shfl_xor(p1, 2);
    p2 += __shfl_xor(p2, 1); p2 += __shfl_xor(p2, 2);
    p3 += __shfl_xor(p3, 1); p3 += __shfl_xor(p3, 2);
    if (q == 0 && grow < NN) {
      el[grow] = p0;      er[grow] = p1;
      el[NN + grow] = p2; er[NN + grow] = p3;
    }
  }
  // ---------- stage 2: z2[e] = h1 @ W2[e] (bf16 out) ----------
  f32x4 acc2[2][4] = {};  // [e][nf]
  for (int k0 = 0; k0 < 128; k0 += 32) {
    int ra = wv * 16 + l15;
    const float* hp = Hs + ra * 132 + k0 + lg * 8;
    float4 h0 = *(const float4*)hp;
    float4 h1v = *(const float4*)(hp + 4);
    float v[8] = {h0.x, h0.y, h0.z, h0.w, h1v.x, h1v.y, h1v.z, h1v.w};
    uint4 hh, ll;
    split_pack8(v, hh, ll);
    short8v ah = *reinterpret_cast<const short8v*>(&hh);
    short8v al = *reinterpret_cast<const short8v*>(&ll);
    #pragma unroll
    for (int e = 0; e < 2; e++) {
      int kgb = e * 16 + (k0 >> 3) + lg;
      #pragma unroll
      for (int nf = 0; nf < 4; nf++) {
        int bslot = kgb * 64 + nf * 16 + l15;
        short8v bh = *reinterpret_cast<const short8v*>(&b2h4[bslot]);
        short8v bl = *reinterpret_cast<const short8v*>(&b2l4[bslot]);
        acc2[e][nf] = __builtin_amdgcn_mfma_f32_16x16x32_bf16(ah, bh, acc2[e][nf], 0, 0, 0);
        acc2[e][nf] = __builtin_amdgcn_mfma_f32_16x16x32_bf16(al, bh, acc2[e][nf], 0, 0, 0);
        acc2[e][nf] = __builtin_amdgcn_mfma_f32_16x16x32_bf16(ah, bl, acc2[e][nf], 0, 0, 0);
      }
    }
  }
  #pragma unroll
  for (int e = 0; e < 2; e++) {
    #pragma unroll
    for (int nf = 0; nf < 4; nf++) {
      #pragma unroll
      for (int reg = 0; reg < 4; reg++) {
        float v = acc2[e][nf][reg];
        float nb = __shfl_xor(v, 1);
        int row = row0 + wv * 16 + lg * 4 + reg;
        if (!(lane & 1) && row < NN) {
          Zb[((size_t)e * NN + row) * 32 + nf * 8 + (l15 >> 1)] = bf_pack(v, nb);
        }
      }
    }
  }
}

// ===== layer2: one-pass alpha + gather bf16 z2 + fc/bias + bf16 h2 + MH dots =====
__global__ __launch_bounds__(256) void agg2_f(
    const int* __restrict__ rowptr, const int* __restrict__ csr_src,
    const float* __restrict__ el, const float* __restrict__ er,
    const uint4* __restrict__ zb, const float* __restrict__ bias,
    const float* __restrict__ fcw, const float* __restrict__ wlm,
    const float* __restrict__ wrm, uint4* __restrict__ h2b,
    float* __restrict__ elm, float* __restrict__ erm) {
  int d = blockIdx.x * 32 + (threadIdx.x >> 3);
  int lane = threadIdx.x & 7;
  if (d >= NN) return;
  int c0 = lane * 8;
  float coef0 = 0.5f * (fcw[0] + fcw[2]);
  float coef1 = 0.5f * (fcw[1] + fcw[3]);
  float hrow[8];
  #pragma unroll
  for (int c = 0; c < 8; c++)
    hrow[c] = coef0 * bias[c0 + c] + coef1 * bias[64 + c0 + c];
  #pragma unroll
  for (int e = 0; e < 2; e++) {
    const int* rp = rowptr + e * 50001;
    const int* cs = csr_src + (size_t)e * EE;
    const float* elp = el + (size_t)e * NN;
    float erd = er[(size_t)e * NN + d];
    const uint4* zp = zb + (size_t)e * NN * 8;
    int j0 = rp[d], j1 = rp[d + 1];
    float sm = 0.f;
    float acc[8] = {};
    for (int j = j0; j < j1; j += 8) {
      int cnt = j1 - j; if (cnt > 8) cnt = 8;
      int jj = j + (lane < cnt ? lane : 0);
      int sl = cs[jj];
      float alv = (lane < cnt) ? __expf(lrelu(elp[sl] + erd)) : 0.f;
      sm += alv;
      int sv[8]; float av[8]; uint4 zv[8];
      #pragma unroll
      for (int k = 0; k < 8; k++) {
        sv[k] = __shfl(sl, k, 8);
        av[k] = __shfl(alv, k, 8);
      }
      #pragma unroll
      for (int k = 0; k < 8; k++) zv[k] = zp[(size_t)sv[k] * 8 + lane];
      #pragma unroll
      for (int k = 0; k < 8; k++) {
        float f[8]; bf_dec8(zv[k], f);
        #pragma unroll
        for (int c = 0; c < 8; c++) acc[c] += av[k] * f[c];
      }
    }
    #pragma unroll
    for (int off = 1; off < 8; off <<= 1) sm += __shfl_xor(sm, off, 8);
    float cinv = (e ? coef1 : coef0) / fmaxf(sm, 1e-9f);
    #pragma unroll
    for (int c = 0; c < 8; c++) hrow[c] += cinv * acc[c];
  }
  uint4 o;
  o.x = bf_pack(hrow[0], hrow[1]); o.y = bf_pack(hrow[2], hrow[3]);
  o.z = bf_pack(hrow[4], hrow[5]); o.w = bf_pack(hrow[6], hrow[7]);
  h2b[(size_t)d * 8 + lane] = o;
  float p[16];
  #pragma unroll
  for (int e2 = 0; e2 < 2; e2++) {
    #pragma unroll
    for (int h = 0; h < 4; h++) {
      const float* a = wlm + (e2 * 4 + h) * 64 + c0;
      const float* b = wrm + (e2 * 4 + h) * 64 + c0;
      float sl = 0.f, sr = 0.f;
      #pragma unroll
      for (int c = 0; c < 8; c++) { sl += hrow[c] * a[c]; sr += hrow[c] * b[c]; }
      p[e2*4+h] = sl; p[8+e2*4+h] = sr;
    }
  }
  #pragma unroll
  for (int off = 1; off < 8; off <<= 1) {
    #pragma unroll
    for (int i = 0; i < 16; i++) p[i] += __shfl_xor(p[i], off, 8);
  }
  if (lane == 0) *(float4*)(elm + (size_t)d * 4)        = make_float4(p[0], p[1], p[2], p[3]);
  if (lane == 1) *(float4*)(elm + ((size_t)NN + d) * 4) = make_float4(p[4], p[5], p[6], p[7]);
  if (lane == 2) *(float4*)(erm + (size_t)d * 4)        = make_float4(p[8], p[9], p[10], p[11]);
  if (lane == 3) *(float4*)(erm + ((size_t)NN + d) * 4) = make_float4(p[12], p[13], p[14], p[15]);
}

// ===== MH aggregation, one-pass softmax; etype = blockIdx.y =====
__global__ __launch_bounds__(256) void agg_mh_k(
    const int* __restrict__ rowptr, const int* __restrict__ csr_src,
    const float* __restrict__ elm, const float* __restrict__ erm,
    const uint4* __restrict__ h2b, float* __restrict__ u) {
  int d = blockIdx.x * 32 + (threadIdx.x >> 3);
  int lane = threadIdx.x & 7, c0 = lane * 8;
  if (d >= NN) return;
  const int e = blockIdx.y;
  const int* rp = rowptr + e * 50001;
  const int* cs = csr_src + (size_t)e * EE;
  const float* elp = elm + (size_t)e * NN * 4;
  float4 er4 = *(const float4*)(erm + ((size_t)e * NN + d) * 4);
  int j0 = rp[d], j1 = rp[d + 1];
  float4 sm = make_float4(0.f, 0.f, 0.f, 0.f);
  float acc[4][8] = {};
  for (int j = j0; j < j1; j += 4) {
    int cnt = j1 - j; if (cnt > 4) cnt = 4;
    int sq[4];
    #pragma unroll
    for (int q = 0; q < 4; q++) sq[q] = cs[j + (q < cnt ? q : 0)];
    float4 vq[4]; uint4 hq[4];
    #pragma unroll
    for (int q = 0; q < 4; q++) vq[q] = *(const float4*)(elp + (size_t)sq[q] * 4);
    #pragma unroll
    for (int q = 0; q < 4; q++) hq[q] = h2b[(size_t)sq[q] * 8 + lane];
    #pragma unroll
    for (int q = 0; q < 4; q++) {
      float g = (q < cnt) ? 1.f : 0.f;
      float4 w;
      w.x = g * __expf(lrelu(vq[q].x + er4.x));
      w.y = g * __expf(lrelu(vq[q].y + er4.y));
      w.z = g * __expf(lrelu(vq[q].z + er4.z));
      w.w = g * __expf(lrelu(vq[q].w + er4.w));
      sm.x += w.x; sm.y += w.y; sm.z += w.z; sm.w += w.w;
      float f[8]; bf_dec8(hq[q], f);
      #pragma unroll
      for (int c = 0; c < 8; c++) {
        acc[0][c] += w.x * f[c];
        acc[1][c] += w.y * f[c];
        acc[2][c] += w.z * f[c];
        acc[3][c] += w.w * f[c];
      }
    }
  }
  float4 inv = make_float4(1.f / fmaxf(sm.x, 1e-9f), 1.f / fmaxf(sm.y, 1e-9f),
                           1.f / fmaxf(sm.z, 1e-9f), 1.f / fmaxf(sm.w, 1e-9f));
  float iv[4] = {inv.x, inv.y, inv.z, inv.w};
  #pragma unroll
  for (int h = 0; h < 4; h++) {
    float* up = u + (((size_t)(e * 4 + h) * NN) + d) * 64 + c0;
    *(float4*)up       = make_float4(acc[h][0]*iv[h], acc[h][1]*iv[h],
                                     acc[h][2]*iv[h], acc[h][3]*iv[h]);
    *(float4*)(up + 4) = make_float4(acc[h][4]*iv[h], acc[h][5]*iv[h],
                                     acc[h][6]*iv[h], acc[h][7]*iv[h]);
  }
}

// ===== column sums of u per (e,h) =====
__global__ __launch_bounds__(256) void colsum_u_k(
    const float* __restrict__ u, float* __restrict__ usum) {
  __shared__ float lds[4][64];
  int eh = blockIdx.x >> 6;
  int chunk = blockIdx.x & 63;
  int c = threadIdx.x & 63, rg = threadIdx.x >> 6;
  const float* up = u + (size_t)eh * NN * 64;
  int n0 = chunk * 782;
  int n1 = n0 + 782; if (n1 > NN) n1 = NN;
  float s = 0.f;
  for (int n = n0 + rg; n < n1; n += 4) s += up[(size_t)n * 64 + c];
  lds[rg][c] = s;
  __syncthreads();
  if (rg == 0) {
    float t = lds[0][c] + lds[1][c] + lds[2][c] + lds[3][c];
    unsafeAtomicAdd(&usum[eh * 64 + c], t);
  }
}

__global__ __launch_bounds__(256) void mean_k(
    const float* __restrict__ usum, const float* __restrict__ Wm,
    float* __restrict__ mean) {
  int c = threadIdx.x;
  int h = c >> 6;
  float s = 0.f;
  for (int e = 0; e < 2; e++) {
    const float* us = usum + (e * 4 + h) * 64;
    const float* wp = Wm + (size_t)e * 64 * 256 + c;
    for (int k = 0; k < 64; k++) s += us[k] * wp[(size_t)k * 256];
  }
  mean[c] = s * (0.5f / NN);
}

// ===== out = 0.5*sum_e u_eh @ Wm_e[:,h*64..] - mean — MFMA =====
__global__ __launch_bounds__(256) void out_gemm_k(
    const float* __restrict__ u, const unsigned short* __restrict__ wmh,
    const unsigned short* __restrict__ wml, const float* __restrict__ mean,
    float* __restrict__ out) {
  __shared__ uint4 AsH[512], AsL[512];
  const int h = blockIdx.y;
  const int tid = threadIdx.x;
  const int row0 = blockIdx.x * 128;
  const int wv = tid >> 6, lane = tid & 63;
  const int l15 = lane & 15, lg = lane >> 4;
  f32x4 acc[2][4] = {};
  const uint4* bh4 = (const uint4*)wmh;
  const uint4* bl4 = (const uint4*)wml;
  for (int e = 0; e < 2; e++) {
    const float* Ap = u + (size_t)(e * 4 + h) * NN * 64;
    for (int k0 = 0; k0 < 64; k0 += 32) {
      {
        int r = tid & 127, half = tid >> 7;
        int rr = row0 + r; if (rr >= NN) rr = NN - 1;
        const float* ap = Ap + (size_t)rr * 64 + k0;
        #pragma unroll
        for (int i = 0; i < 2; i++) {
          int kg = half * 2 + i;
          float4 a0 = *(const float4*)(ap + kg * 8);
          float4 a1 = *(const float4*)(ap + kg * 8 + 4);
          float v[8] = {a0.x, a0.y, a0.z, a0.w, a1.x, a1.y, a1.z, a1.w};
          uint4 hh, ll;
          split_pack8(v, hh, ll);
          AsH[kg * 128 + r] = hh;
          AsL[kg * 128 + r] = ll;
        }
      }
      __syncthreads();
      short8v ah[2], al[2];
      #pragma unroll
      for (int mf = 0; mf < 2; mf++) {
        int slot = lg * 128 + wv * 32 + mf * 16 + l15;
        ah[mf] = *reinterpret_cast<const short8v*>(&AsH[slot]);
        al[mf] = *reinterpret_cast<const short8v*>(&AsL[slot]);
      }
      int kgb = e * 8 + (k0 >> 3) + lg;
      #pragma unroll
      for (int nf = 0; nf < 4; nf++) {
        int bslot = kgb * 256 + h * 64 + nf * 16 + l15;
        short8v bh = *reinterpret_cast<const short8v*>(&bh4[bslot]);
        short8v bl = *reinterpret_cast<const short8v*>(&bl4[bslot]);
        #pragma unroll
        for (int mf = 0; mf < 2; mf++) {
          acc[mf][nf] = __builtin_amdgcn_mfma_f32_16x16x32_bf16(ah[mf], bh, acc[mf][nf], 0, 0, 0);
          acc[mf][nf] = __builtin_amdgcn_mfma_f32_16x16x32_bf16(al[mf], bh, acc[mf][nf], 0, 0, 0);
          acc[mf][nf] = __builtin_amdgcn_mfma_f32_16x16x32_bf16(ah[mf], bl, acc[mf][nf], 0, 0, 0);
        }
      }
      __syncthreads();
    }
  }
  #pragma unroll
  for (int nf = 0; nf < 4; nf++) {
    int col = nf * 16 + l15;
    float mn = mean[h * 64 + col];
    #pragma unroll
    for (int mf = 0; mf < 2; mf++) {
      #pragma unroll
      for (int reg = 0; reg < 4; reg++) {
        int row = row0 + wv * 32 + mf * 16 + lg * 4 + reg;
        if (row < NN)
          out[(size_t)row * 256 + h * 64 + col] = 0.5f * acc[mf][nf][reg] - mn;
      }
    }
  }
}

// ================= host-side launch =================
extern "C" void kernel_launch(void* const* d_in, const int* in_sizes, int n_in,
                              void* d_out, int out_size, void* d_ws, size_t ws_size,
                              hipStream_t stream) {
  const float* x  = (const float*)d_in[0];
  const int* src0 = (const int*)d_in[1];
  const int* dst0 = (const int*)d_in[2];
  const int* src1 = (const int*)d_in[3];
  const int* dst1 = (const int*)d_in[4];
  const float* W1  = (const float*)d_in[5];
  const float* al1 = (const float*)d_in[6];
  const float* ar1 = (const float*)d_in[7];
  const float* b1  = (const float*)d_in[8];
  const float* W2  = (const float*)d_in[9];
  const float* al2 = (const float*)d_in[10];
  const float* ar2 = (const float*)d_in[11];
  const float* b2  = (const float*)d_in[12];
  const float* Wm  = (const float*)d_in[13];
  const float* alm = (const float*)d_in[14];
  const float* arm = (const float*)d_in[15];
  // d_in[16] = bm: cancels under per-head mean-centering
  const float* fcw = (const float*)d_in[17];
  float* out = (float*)d_out;

  float* ws = (float*)d_ws;
  float* zu     = ws;                                  // u1 fp32 12.8M / u 25.6M
  unsigned int* z2b = (unsigned int*)(ws + 12800000);  // bf16 z2, 3.2M uints
  unsigned int* xb = (unsigned int*)(ws + 25600000);   // bf16 x, 3.2M uints
  unsigned int* h2b = (unsigned int*)(ws + 32000000);  // 1.6M uints
  float* el     = ws + 33600000;   // 0.4M
  float* er     = ws + 34000000;   // 0.4M
  float* elm    = ws + 34400000;   // 0.4M
  float* erm    = ws + 34800000;   // 0.4M
  float* wl1    = ws + 35200000;
  float* wr1    = wl1 + 256;
  float* wl2    = wr1 + 256;
  float* wr2    = wl2 + 256;
  float* wlm    = wr2 + 256;
  float* wrm    = wlm + 512;
  float* usum   = wrm + 512;
  float* meanp  = usum + 512;
  int* rowptr  = (int*)(meanp + 256);          // 2*50001
  int* csr_src = rowptr + 100002;              // 2*EE
  // pre-split weights (bf16 hi/lo, frag-linear), 16B-aligned
  unsigned short* w1h = (unsigned short*)(csr_src + 2 * EE + 2);
  unsigned short* w1l = w1h + 32768;
  unsigned short* w2h = w1l + 32768;
  unsigned short* w2l = w2h + 16384;
  unsigned short* wmh = w2l + 16384;
  unsigned short* wml = wmh + 32768;
  // CSR-build temporaries (zu region free until agg_x_f)
  int* rel    = (int*)zu;                      // 2*EE ints
  int* deg_p  = (int*)zu + 2 * EE;             // 8 label-private copies: 800000
  int* deg    = (int*)zu + 2 * EE + 800000;    // totals: 100000
  int* inc    = deg + 100000;                  // 100000
  int* bsum   = inc + 100000;                  // 256

  hipMemsetAsync(deg_p, 0, 800000 * sizeof(int), stream);
  hipMemsetAsync(usum, 0, 512 * sizeof(float), stream);
  fold_k<<<8, 256, 0, stream>>>(W1, al1, ar1, W2, al2, ar2, Wm, alm, arm,
                                wl1, wr1, wl2, wr2, wlm, wrm);
  // passA (label-private atomics) ∥ xdot ∥ wtrans
  front_k<<<5008, 256, 0, stream>>>(dst0, dst1, deg_p, rel,
                                    x, wl1, wr1, xb, el, er,
                                    W1, W2, Wm, w1h, w1l, w2h, w2l, wmh, wml);
  combine_k<<<391, 256, 0, stream>>>(deg_p, deg);
  scan1_k<<<dim3(98, 2), 512, 0, stream>>>(deg, inc, bsum);
  scan2_k<<<2, 128, 0, stream>>>(bsum, 98);
  scan3_k<<<dim3(196, 2), 256, 0, stream>>>(deg, inc, bsum, rowptr);
  passB_k<<<8 * SC_BPR, 256, 0, stream>>>(src0, dst0, src1, dst1,
                                          rel, rowptr, deg_p, csr_src);

  // ================= layer 1 =================
  agg_x_f<<<dim3(3125, 2), 256, 0, stream>>>(rowptr, csr_src, el, er,
                                             (const uint4*)xb, zu);
  layer12_k<<<782, 256, 0, stream>>>(zu, w1h, w1l, b1, w2h, w2l, wl2, wr2,
                                     z2b, el, er);

  // ================= layer 2 =================
  agg2_f<<<1563, 256, 0, stream>>>(rowptr, csr_src, el, er, (const uint4*)z2b,
                                   b2, fcw, wlm, wrm, (uint4*)h2b, elm, erm);

  // ================= MH layer =================
  agg_mh_k<<<dim3(1563, 2), 256, 0, stream>>>(rowptr, csr_src, elm, erm,
                                              (const uint4*)h2b, zu);
  colsum_u_k<<<512, 256, 0, stream>>>(zu, usum);
  mean_k<<<1, 256, 0, stream>>>(usum, Wm, meanp);
  out_gemm_k<<<dim3(391, 4), 256, 0, stream>>>(zu, wmh, wml, meanp, out);
}

// Round 15
// 527.519 us; speedup vs baseline: 1.0304x; 1.0304x over previous
//
#include <hip/hip_runtime.h>

#define NN 50000
#define EE 800000

using short8v = __attribute__((ext_vector_type(8))) short;
using f32x4 = __attribute__((ext_vector_type(4))) float;

// ---------------- bf16 helpers ----------------
__device__ inline unsigned int bf_pack(float lo, float hi) {
  unsigned int a = __float_as_uint(lo);
  a += 0x7FFFu + ((a >> 16) & 1u);
  unsigned int b = __float_as_uint(hi);
  b += 0x7FFFu + ((b >> 16) & 1u);
  return (a >> 16) | ((b >> 16) << 16);
}
__device__ inline void bf_dec8(uint4 v, float* f) {
  f[0] = __uint_as_float(v.x << 16); f[1] = __uint_as_float(v.x & 0xFFFF0000u);
  f[2] = __uint_as_float(v.y << 16); f[3] = __uint_as_float(v.y & 0xFFFF0000u);
  f[4] = __uint_as_float(v.z << 16); f[5] = __uint_as_float(v.z & 0xFFFF0000u);
  f[6] = __uint_as_float(v.w << 16); f[7] = __uint_as_float(v.w & 0xFFFF0000u);
}
__device__ inline float lrelu(float v) { return v >= 0.f ? v : 0.2f * v; }

// truncation split of 8 fp32 into bf16 hi + bf16 lo (packed as uint4 each).
__device__ inline void split_pack8(const float* v, uint4& h, uint4& l) {
  unsigned int hb[8], lb[8];
  #pragma unroll
  for (int j = 0; j < 8; j++) {
    unsigned int b = __float_as_uint(v[j]);
    hb[j] = b & 0xFFFF0000u;
    float r = v[j] - __uint_as_float(hb[j]);
    lb[j] = __float_as_uint(r) & 0xFFFF0000u;
  }
  h.x = (hb[0] >> 16) | hb[1]; h.y = (hb[2] >> 16) | hb[3];
  h.z = (hb[4] >> 16) | hb[5]; h.w = (hb[6] >> 16) | hb[7];
  l.x = (lb[0] >> 16) | lb[1]; l.y = (lb[2] >> 16) | lb[3];
  l.z = (lb[4] >> 16) | lb[5]; l.w = (lb[6] >> 16) | lb[7];
}

#define SC_BPR 256

// ======== fold a_l/a_r through weights (must precede front_k: xdot uses wl1) ==
__global__ __launch_bounds__(256) void fold_k(
    const float* __restrict__ W1, const float* __restrict__ al1, const float* __restrict__ ar1,
    const float* __restrict__ W2, const float* __restrict__ al2, const float* __restrict__ ar2,
    const float* __restrict__ Wm, const float* __restrict__ alm, const float* __restrict__ arm,
    float* __restrict__ wl1, float* __restrict__ wr1,
    float* __restrict__ wl2, float* __restrict__ wr2,
    float* __restrict__ wlm, float* __restrict__ wrm) {
  int t = blockIdx.x * 256 + threadIdx.x;
  if (t < 512) {
    int lr = t >> 8, e = (t >> 7) & 1, k = t & 127;
    const float* a = (lr ? ar1 : al1) + e * 128;
    const float* w = W1 + ((size_t)e * 128 + k) * 128;
    float s = 0.f;
    for (int f = 0; f < 128; f++) s += w[f] * a[f];
    (lr ? wr1 : wl1)[e * 128 + k] = s;
  } else if (t < 1024) {
    int u = t - 512;
    int lr = u >> 8, e = (u >> 7) & 1, k = u & 127;
    const float* a = (lr ? ar2 : al2) + e * 64;
    const float* w = W2 + ((size_t)e * 128 + k) * 64;
    float s = 0.f;
    for (int f = 0; f < 64; f++) s += w[f] * a[f];
    (lr ? wr2 : wl2)[e * 128 + k] = s;
  } else if (t < 2048) {
    int u = t - 1024;
    int lr = u >> 9, e = (u >> 8) & 1, h = (u >> 6) & 3, k = u & 63;
    const float* a = (lr ? arm : alm) + (e * 4 + h) * 64;
    const float* w = Wm + ((size_t)e * 64 + k) * 256 + h * 64;
    float s = 0.f;
    for (int f = 0; f < 64; f++) s += w[f] * a[f];
    (lr ? wrm : wlm)[(e * 4 + h) * 64 + k] = s;
  }
}

// ===== front_k: grid-union of {passA (atomic rank gen), xdot, wtrans} ======
// blocks [0,1563): passA | [1563,4688): xdot | [4688,5008): wtrans.
__global__ __launch_bounds__(256) void front_k(
    const int* __restrict__ dst0, const int* __restrict__ dst1,
    int* __restrict__ deg, int* __restrict__ rel,
    const float* __restrict__ x, const float* __restrict__ wl,
    const float* __restrict__ wr, unsigned int* __restrict__ xb,
    float* __restrict__ el, float* __restrict__ er,
    const float* __restrict__ W1, const float* __restrict__ W2,
    const float* __restrict__ Wm,
    unsigned short* __restrict__ w1h, unsigned short* __restrict__ w1l,
    unsigned short* __restrict__ w2h, unsigned short* __restrict__ w2l,
    unsigned short* __restrict__ wmh, unsigned short* __restrict__ wml) {
  const int blk = blockIdx.x;
  if (blk < 1563) {
    int i = blk * 256 + threadIdx.x;
    if (i < 200000) {
      int4 d = ((const int4*)dst0)[i];
      int4 r;
      r.x = atomicAdd(&deg[d.x], 1);
      r.y = atomicAdd(&deg[d.y], 1);
      r.z = atomicAdd(&deg[d.z], 1);
      r.w = atomicAdd(&deg[d.w], 1);
      ((int4*)rel)[i] = r;
    } else if (i < 400000) {
      int4 d = ((const int4*)dst1)[i - 200000];
      int* dg = deg + 50000;
      int4 r;
      r.x = atomicAdd(&dg[d.x], 1);
      r.y = atomicAdd(&dg[d.y], 1);
      r.z = atomicAdd(&dg[d.z], 1);
      r.w = atomicAdd(&dg[d.w], 1);
      ((int4*)(rel + EE))[i - 200000] = r;
    }
  } else if (blk < 4688) {
    int bx = blk - 1563;
    int n = bx * 16 + (threadIdx.x >> 4);
    int lane = threadIdx.x & 15;
    if (n >= NN) return;
    float p[4] = {0.f, 0.f, 0.f, 0.f};
    #pragma unroll
    for (int i = 0; i < 2; i++) {
      int c = (lane + i * 16) * 4;
      float4 xv = *(const float4*)(x + (size_t)n * 128 + c);
      uint2 o;
      o.x = bf_pack(xv.x, xv.y);
      o.y = bf_pack(xv.z, xv.w);
      *(uint2*)(xb + (size_t)n * 64 + c / 2) = o;
      #pragma unroll
      for (int e = 0; e < 2; e++) {
        float4 a = *(const float4*)(wl + e * 128 + c);
        float4 b = *(const float4*)(wr + e * 128 + c);
        p[e*2+0] += xv.x*a.x + xv.y*a.y + xv.z*a.z + xv.w*a.w;
        p[e*2+1] += xv.x*b.x + xv.y*b.y + xv.z*b.z + xv.w*b.w;
      }
    }
    #pragma unroll
    for (int off = 1; off < 16; off <<= 1) {
      #pragma unroll
      for (int i = 0; i < 4; i++) p[i] += __shfl_xor(p[i], off);
    }
    if (lane == 0) {
      el[n] = p[0]; er[n] = p[1];
      el[NN + n] = p[2]; er[NN + n] = p[3];
    }
  } else {
    int t = (blk - 4688) * 256 + threadIdx.x;
    float v; unsigned short *ph, *pl; int oi;
    if (t < 32768) {                       // W1: K=128 (KG=16), N=128
      int j = t & 7, n = (t >> 3) & 127, kg = (t >> 10) & 15, e = t >> 14;
      v = W1[((size_t)(e * 128 + kg * 8 + j)) * 128 + n];
      ph = w1h; pl = w1l; oi = t;
    } else if (t < 49152) {                // W2: K=128 (KG=16), N=64
      int i = t - 32768;
      int j = i & 7, n = (i >> 3) & 63, kg = (i >> 9) & 15, e = i >> 13;
      v = W2[((size_t)(e * 128 + kg * 8 + j)) * 64 + n];
      ph = w2h; pl = w2l; oi = i;
    } else if (t < 81920) {                // Wm: K=64 (KG=8), N=256
      int i = t - 49152;
      int j = i & 7, n = (i >> 3) & 255, kg = (i >> 11) & 7, e = i >> 14;
      v = Wm[((size_t)(e * 64 + kg * 8 + j)) * 256 + n];
      ph = wmh; pl = wml; oi = i;
    } else return;
    unsigned int b = __float_as_uint(v);
    unsigned int hb = b & 0xFFFF0000u;
    float r = v - __uint_as_float(hb);
    unsigned int lb = __float_as_uint(r);
    ph[oi] = (unsigned short)(hb >> 16);
    pl[oi] = (unsigned short)(lb >> 16);
  }
}

__global__ __launch_bounds__(512) void scan1_k(const int* __restrict__ deg,
                                               int* __restrict__ inc,
                                               int* __restrict__ bsum) {
  __shared__ int s[512];
  int e = blockIdx.y;
  int t = threadIdx.x, i = blockIdx.x * 512 + t;
  int v = (i < NN) ? deg[e * 50000 + i] : 0;
  s[t] = v; __syncthreads();
  #pragma unroll
  for (int off = 1; off < 512; off <<= 1) {
    int u = (t >= off) ? s[t - off] : 0;
    __syncthreads();
    s[t] += u;
    __syncthreads();
  }
  if (i < NN) inc[e * 50000 + i] = s[t];
  if (t == 511) bsum[e * 128 + blockIdx.x] = s[511];
}

__global__ __launch_bounds__(128) void scan2_k(int* __restrict__ bsum, int nb) {
  __shared__ int s[128];
  int e = blockIdx.x;
  int t = threadIdx.x;
  int v = (t < nb) ? bsum[e * 128 + t] : 0;
  s[t] = v; __syncthreads();
  #pragma unroll
  for (int off = 1; off < 128; off <<= 1) {
    int u = (t >= off) ? s[t - off] : 0;
    __syncthreads();
    s[t] += u;
    __syncthreads();
  }
  if (t < nb) bsum[e * 128 + t] = s[t] - v;
}

__global__ __launch_bounds__(256) void scan3_k(const int* __restrict__ deg,
                                               const int* __restrict__ inc,
                                               const int* __restrict__ bsum,
                                               int* __restrict__ rowptr) {
  int e = blockIdx.y;
  int i = blockIdx.x * 256 + threadIdx.x;
  if (i < NN) {
    rowptr[e * 50001 + i] =
        inc[e * 50000 + i] - deg[e * 50000 + i] + bsum[e * 128 + (i >> 9)];
  }
  if (i == NN) rowptr[e * 50001 + NN] = EE;
}

// passB: atomic-free placement. XCD-partitioned by dst range (write locality);
// rowptr slice held in LDS so per-match cost = LDS read + L2-local store.
__global__ __launch_bounds__(256) void passB_k(
    const int* __restrict__ src0, const int* __restrict__ dst0,
    const int* __restrict__ src1, const int* __restrict__ dst1,
    const int* __restrict__ rel, const int* __restrict__ rowptr,
    int* __restrict__ csr_src) {
  __shared__ int rp_s[2][6250];
  const int range = blockIdx.x & 7;
  const int bpr = blockIdx.x >> 3;
  const int lo = range * 6250;
  const int hi = lo + 6250;
  for (int k = threadIdx.x; k < 6250; k += 256) {
    rp_s[0][k] = rowptr[lo + k];
    rp_s[1][k] = rowptr[50001 + lo + k];
  }
  __syncthreads();
  #pragma unroll
  for (int e = 0; e < 2; e++) {
    const int4* ds4 = (const int4*)(e ? dst1 : dst0);
    const int* ss = e ? src1 : src0;
    const int4* rl4 = (const int4*)(rel + (size_t)e * EE);
    const int* rps = rp_s[e];
    int* outp = csr_src + (size_t)e * EE;
    for (int i = bpr * 256 + threadIdx.x; i < EE / 4; i += SC_BPR * 256) {
      int4 d = ds4[i];
      int4 rl = rl4[i];
      int b = i * 4;
      if (d.x >= lo && d.x < hi) outp[rps[d.x - lo] + rl.x] = ss[b];
      if (d.y >= lo && d.y < hi) outp[rps[d.y - lo] + rl.y] = ss[b + 1];
      if (d.z >= lo && d.z < hi) outp[rps[d.z - lo] + rl.z] = ss[b + 2];
      if (d.w >= lo && d.w < hi) outp[rps[d.w - lo] + rl.w] = ss[b + 3];
    }
  }
}

// ===== layer1: one-pass alpha + gather of bf16 x; etype = blockIdx.y =====
// Loads issued in static batches of 8 (named registers).
__global__ __launch_bounds__(256) void agg_x_f(
    const int* __restrict__ rowptr, const int* __restrict__ csr_src,
    const float* __restrict__ el, const float* __restrict__ er,
    const uint4* __restrict__ xb, float* __restrict__ u1) {
  int d = blockIdx.x * 16 + (threadIdx.x >> 4);
  int lane = threadIdx.x & 15;
  if (d >= NN) return;
  const int e = blockIdx.y;
  const int* rp = rowptr + e * 50001;
  const int* cs = csr_src + (size_t)e * EE;
  const float* elp = el + (size_t)e * NN;
  float erd = er[(size_t)e * NN + d];
  int j0 = rp[d], j1 = rp[d + 1];
  float sm = 0.f;
  float acc[8] = {};
  for (int j = j0; j < j1; j += 16) {
    int cnt = j1 - j; if (cnt > 16) cnt = 16;
    int jj = j + (lane < cnt ? lane : 0);
    int sl = cs[jj];
    float alv = (lane < cnt) ? __expf(lrelu(elp[sl] + erd)) : 0.f;
    sm += alv;
    {
      int sv[8]; float av[8]; uint4 xv[8];
      #pragma unroll
      for (int k = 0; k < 8; k++) {
        sv[k] = __shfl(sl, k, 16);
        av[k] = __shfl(alv, k, 16);
      }
      #pragma unroll
      for (int k = 0; k < 8; k++) xv[k] = xb[(size_t)sv[k] * 16 + lane];
      #pragma unroll
      for (int k = 0; k < 8; k++) {
        float f[8]; bf_dec8(xv[k], f);
        #pragma unroll
        for (int c = 0; c < 8; c++) acc[c] += av[k] * f[c];
      }
    }
    if (cnt > 8) {
      int sv[8]; float av[8]; uint4 xv[8];
      #pragma unroll
      for (int k = 0; k < 8; k++) {
        sv[k] = __shfl(sl, 8 + k, 16);
        av[k] = __shfl(alv, 8 + k, 16);
      }
      #pragma unroll
      for (int k = 0; k < 8; k++) xv[k] = xb[(size_t)sv[k] * 16 + lane];
      #pragma unroll
      for (int k = 0; k < 8; k++) {
        float f[8]; bf_dec8(xv[k], f);
        #pragma unroll
        for (int c = 0; c < 8; c++) acc[c] += av[k] * f[c];
      }
    }
  }
  #pragma unroll
  for (int off = 1; off < 16; off <<= 1) sm += __shfl_xor(sm, off, 16);
  float inv = 1.f / fmaxf(sm, 1e-9f);
  float* up = u1 + ((size_t)e * NN + d) * 128 + lane * 8;
  *(float4*)up       = make_float4(acc[0]*inv, acc[1]*inv, acc[2]*inv, acc[3]*inv);
  *(float4*)(up + 4) = make_float4(acc[4]*inv, acc[5]*inv, acc[6]*inv, acc[7]*inv);
}

// ===== fused layer1-GEMM + layer2 dots + layer2-GEMM (h1 stays in LDS) =====
// BM=64: LDS 33.8 KB -> 4 blocks/CU, 782 blocks. Each wave owns 16 rows.
__global__ __launch_bounds__(256) void layer12_k(
    const float* __restrict__ u1, const unsigned short* __restrict__ w1h,
    const unsigned short* __restrict__ w1l, const float* __restrict__ b1,
    const unsigned short* __restrict__ w2h, const unsigned short* __restrict__ w2l,
    const float* __restrict__ wl2, const float* __restrict__ wr2,
    unsigned int* __restrict__ Zb, float* __restrict__ el,
    float* __restrict__ er) {
  __shared__ float smem[64 * 132];            // 33.8 KB; staging aliased
  uint4* AsH = (uint4*)smem;                  // 256 uint4 = 4 KB
  uint4* AsL = AsH + 256;                     // 4 KB
  float* Hs = smem;
  const int tid = threadIdx.x;
  const int row0 = blockIdx.x * 64;
  const int wv = tid >> 6, lane = tid & 63;
  const int l15 = lane & 15, lg = lane >> 4;
  const uint4* b1h4 = (const uint4*)w1h;
  const uint4* b1l4 = (const uint4*)w1l;
  const uint4* b2h4 = (const uint4*)w2h;
  const uint4* b2l4 = (const uint4*)w2l;

  // ---------- stage 1: h1 = 0.5*(u1[0]@W1[0]+u1[1]@W1[1]) + bias ----------
  f32x4 acc[8] = {};
  for (int e = 0; e < 2; e++) {
    const float* Ap = u1 + (size_t)e * NN * 128;
    for (int k0 = 0; k0 < 128; k0 += 32) {
      {
        int r = tid & 63, kgl = tid >> 6;    // 64 rows x 4 kgroups
        int rr = row0 + r; if (rr >= NN) rr = NN - 1;
        const float* ap = Ap + (size_t)rr * 128 + k0 + kgl * 8;
        float4 a0 = *(const float4*)ap;
        float4 a1 = *(const float4*)(ap + 4);
        float v[8] = {a0.x, a0.y, a0.z, a0.w, a1.x, a1.y, a1.z, a1.w};
        uint4 hh, ll;
        split_pack8(v, hh, ll);
        AsH[kgl * 64 + r] = hh;
        AsL[kgl * 64 + r] = ll;
      }
      __syncthreads();
      int slot = lg * 64 + wv * 16 + l15;
      short8v ah = *reinterpret_cast<const short8v*>(&AsH[slot]);
      short8v al = *reinterpret_cast<const short8v*>(&AsL[slot]);
      int kgb = e * 16 + (k0 >> 3) + lg;
      #pragma unroll
      for (int nf = 0; nf < 8; nf++) {
        int bslot = kgb * 128 + nf * 16 + l15;
        short8v bh = *reinterpret_cast<const short8v*>(&b1h4[bslot]);
        short8v bl = *reinterpret_cast<const short8v*>(&b1l4[bslot]);
        acc[nf] = __builtin_amdgcn_mfma_f32_16x16x32_bf16(ah, bh, acc[nf], 0, 0, 0);
        acc[nf] = __builtin_amdgcn_mfma_f32_16x16x32_bf16(al, bh, acc[nf], 0, 0, 0);
        acc[nf] = __builtin_amdgcn_mfma_f32_16x16x32_bf16(ah, bl, acc[nf], 0, 0, 0);
      }
      __syncthreads();
    }
  }
  // ---------- h1 -> LDS (f32, pitch 132) ----------
  #pragma unroll
  for (int nf = 0; nf < 8; nf++) {
    int col = nf * 16 + l15;
    float bb = 0.5f * (b1[col] + b1[128 + col]);
    #pragma unroll
    for (int reg = 0; reg < 4; reg++) {
      int rloc = wv * 16 + lg * 4 + reg;
      Hs[rloc * 132 + col] = 0.5f * acc[nf][reg] + bb;
    }
  }
  __syncthreads();
  // ---------- layer2 el/er dots (4 threads/row, interleaved cols) ----------
  {
    int r = tid >> 2, q = tid & 3;
    int grow = row0 + r;
    const float* hrow = Hs + r * 132;
    float p0 = 0.f, p1 = 0.f, p2 = 0.f, p3 = 0.f;
    #pragma unroll 8
    for (int c = 0; c < 32; c++) {
      int k = q + c * 4;
      float hv = hrow[k];
      p0 += hv * wl2[k];       p1 += hv * wr2[k];
      p2 += hv * wl2[128 + k]; p3 += hv * wr2[128 + k];
    }
    p0 += __shfl_xor(p0, 1); p0 += __shfl_xor(p0, 2);
    p1 += __shfl_xor(p1, 1); p1 += __shfl_xor(p1, 2);
    p2 += __shfl_xor(p2, 1); p2 += __shfl_xor(p2, 2);
    p3 += __shfl_xor(p3, 1); p3 += __shfl_xor(p3, 2);
    if (q == 0 && grow < NN) {
      el[grow] = p0;      er[grow] = p1;
      el[NN + grow] = p2; er[NN + grow] = p3;
    }
  }
  // ---------- stage 2: z2[e] = h1 @ W2[e] (bf16 out) ----------
  f32x4 acc2[2][4] = {};  // [e][nf]
  for (int k0 = 0; k0 < 128; k0 += 32) {
    int ra = wv * 16 + l15;
    const float* hp = Hs + ra * 132 + k0 + lg * 8;
    float4 h0 = *(const float4*)hp;
    float4 h1v = *(const float4*)(hp + 4);
    float v[8] = {h0.x, h0.y, h0.z, h0.w, h1v.x, h1v.y, h1v.z, h1v.w};
    uint4 hh, ll;
    split_pack8(v, hh, ll);
    short8v ah = *reinterpret_cast<const short8v*>(&hh);
    short8v al = *reinterpret_cast<const short8v*>(&ll);
    #pragma unroll
    for (int e = 0; e < 2; e++) {
      int kgb = e * 16 + (k0 >> 3) + lg;
      #pragma unroll
      for (int nf = 0; nf < 4; nf++) {
        int bslot = kgb * 64 + nf * 16 + l15;
        short8v bh = *reinterpret_cast<const short8v*>(&b2h4[bslot]);
        short8v bl = *reinterpret_cast<const short8v*>(&b2l4[bslot]);
        acc2[e][nf] = __builtin_amdgcn_mfma_f32_16x16x32_bf16(ah, bh, acc2[e][nf], 0, 0, 0);
        acc2[e][nf] = __builtin_amdgcn_mfma_f32_16x16x32_bf16(al, bh, acc2[e][nf], 0, 0, 0);
        acc2[e][nf] = __builtin_amdgcn_mfma_f32_16x16x32_bf16(ah, bl, acc2[e][nf], 0, 0, 0);
      }
    }
  }
  #pragma unroll
  for (int e = 0; e < 2; e++) {
    #pragma unroll
    for (int nf = 0; nf < 4; nf++) {
      #pragma unroll
      for (int reg = 0; reg < 4; reg++) {
        float v = acc2[e][nf][reg];
        float nb = __shfl_xor(v, 1);
        int row = row0 + wv * 16 + lg * 4 + reg;
        if (!(lane & 1) && row < NN) {
          Zb[((size_t)e * NN + row) * 32 + nf * 8 + (l15 >> 1)] = bf_pack(v, nb);
        }
      }
    }
  }
}

// ===== layer2: one-pass alpha + gather bf16 z2 + fc/bias + bf16 h2 + MH dots =====
__global__ __launch_bounds__(256) void agg2_f(
    const int* __restrict__ rowptr, const int* __restrict__ csr_src,
    const float* __restrict__ el, const float* __restrict__ er,
    const uint4* __restrict__ zb, const float* __restrict__ bias,
    const float* __restrict__ fcw, const float* __restrict__ wlm,
    const float* __restrict__ wrm, uint4* __restrict__ h2b,
    float* __restrict__ elm, float* __restrict__ erm) {
  int d = blockIdx.x * 32 + (threadIdx.x >> 3);
  int lane = threadIdx.x & 7;
  if (d >= NN) return;
  int c0 = lane * 8;
  float coef0 = 0.5f * (fcw[0] + fcw[2]);
  float coef1 = 0.5f * (fcw[1] + fcw[3]);
  float hrow[8];
  #pragma unroll
  for (int c = 0; c < 8; c++)
    hrow[c] = coef0 * bias[c0 + c] + coef1 * bias[64 + c0 + c];
  #pragma unroll
  for (int e = 0; e < 2; e++) {
    const int* rp = rowptr + e * 50001;
    const int* cs = csr_src + (size_t)e * EE;
    const float* elp = el + (size_t)e * NN;
    float erd = er[(size_t)e * NN + d];
    const uint4* zp = zb + (size_t)e * NN * 8;
    int j0 = rp[d], j1 = rp[d + 1];
    float sm = 0.f;
    float acc[8] = {};
    for (int j = j0; j < j1; j += 8) {
      int cnt = j1 - j; if (cnt > 8) cnt = 8;
      int jj = j + (lane < cnt ? lane : 0);
      int sl = cs[jj];
      float alv = (lane < cnt) ? __expf(lrelu(elp[sl] + erd)) : 0.f;
      sm += alv;
      int sv[8]; float av[8]; uint4 zv[8];
      #pragma unroll
      for (int k = 0; k < 8; k++) {
        sv[k] = __shfl(sl, k, 8);
        av[k] = __shfl(alv, k, 8);
      }
      #pragma unroll
      for (int k = 0; k < 8; k++) zv[k] = zp[(size_t)sv[k] * 8 + lane];
      #pragma unroll
      for (int k = 0; k < 8; k++) {
        float f[8]; bf_dec8(zv[k], f);
        #pragma unroll
        for (int c = 0; c < 8; c++) acc[c] += av[k] * f[c];
      }
    }
    #pragma unroll
    for (int off = 1; off < 8; off <<= 1) sm += __shfl_xor(sm, off, 8);
    float cinv = (e ? coef1 : coef0) / fmaxf(sm, 1e-9f);
    #pragma unroll
    for (int c = 0; c < 8; c++) hrow[c] += cinv * acc[c];
  }
  uint4 o;
  o.x = bf_pack(hrow[0], hrow[1]); o.y = bf_pack(hrow[2], hrow[3]);
  o.z = bf_pack(hrow[4], hrow[5]); o.w = bf_pack(hrow[6], hrow[7]);
  h2b[(size_t)d * 8 + lane] = o;
  float p[16];
  #pragma unroll
  for (int e2 = 0; e2 < 2; e2++) {
    #pragma unroll
    for (int h = 0; h < 4; h++) {
      const float* a = wlm + (e2 * 4 + h) * 64 + c0;
      const float* b = wrm + (e2 * 4 + h) * 64 + c0;
      float sl = 0.f, sr = 0.f;
      #pragma unroll
      for (int c = 0; c < 8; c++) { sl += hrow[c] * a[c]; sr += hrow[c] * b[c]; }
      p[e2*4+h] = sl; p[8+e2*4+h] = sr;
    }
  }
  #pragma unroll
  for (int off = 1; off < 8; off <<= 1) {
    #pragma unroll
    for (int i = 0; i < 16; i++) p[i] += __shfl_xor(p[i], off, 8);
  }
  if (lane == 0) *(float4*)(elm + (size_t)d * 4)        = make_float4(p[0], p[1], p[2], p[3]);
  if (lane == 1) *(float4*)(elm + ((size_t)NN + d) * 4) = make_float4(p[4], p[5], p[6], p[7]);
  if (lane == 2) *(float4*)(erm + (size_t)d * 4)        = make_float4(p[8], p[9], p[10], p[11]);
  if (lane == 3) *(float4*)(erm + ((size_t)NN + d) * 4) = make_float4(p[12], p[13], p[14], p[15]);
}

// ===== MH aggregation, one-pass softmax; etype = blockIdx.y =====
__global__ __launch_bounds__(256) void agg_mh_k(
    const int* __restrict__ rowptr, const int* __restrict__ csr_src,
    const float* __restrict__ elm, const float* __restrict__ erm,
    const uint4* __restrict__ h2b, float* __restrict__ u) {
  int d = blockIdx.x * 32 + (threadIdx.x >> 3);
  int lane = threadIdx.x & 7, c0 = lane * 8;
  if (d >= NN) return;
  const int e = blockIdx.y;
  const int* rp = rowptr + e * 50001;
  const int* cs = csr_src + (size_t)e * EE;
  const float* elp = elm + (size_t)e * NN * 4;
  float4 er4 = *(const float4*)(erm + ((size_t)e * NN + d) * 4);
  int j0 = rp[d], j1 = rp[d + 1];
  float4 sm = make_float4(0.f, 0.f, 0.f, 0.f);
  float acc[4][8] = {};
  for (int j = j0; j < j1; j += 4) {
    int cnt = j1 - j; if (cnt > 4) cnt = 4;
    int sq[4];
    #pragma unroll
    for (int q = 0; q < 4; q++) sq[q] = cs[j + (q < cnt ? q : 0)];
    float4 vq[4]; uint4 hq[4];
    #pragma unroll
    for (int q = 0; q < 4; q++) vq[q] = *(const float4*)(elp + (size_t)sq[q] * 4);
    #pragma unroll
    for (int q = 0; q < 4; q++) hq[q] = h2b[(size_t)sq[q] * 8 + lane];
    #pragma unroll
    for (int q = 0; q < 4; q++) {
      float g = (q < cnt) ? 1.f : 0.f;
      float4 w;
      w.x = g * __expf(lrelu(vq[q].x + er4.x));
      w.y = g * __expf(lrelu(vq[q].y + er4.y));
      w.z = g * __expf(lrelu(vq[q].z + er4.z));
      w.w = g * __expf(lrelu(vq[q].w + er4.w));
      sm.x += w.x; sm.y += w.y; sm.z += w.z; sm.w += w.w;
      float f[8]; bf_dec8(hq[q], f);
      #pragma unroll
      for (int c = 0; c < 8; c++) {
        acc[0][c] += w.x * f[c];
        acc[1][c] += w.y * f[c];
        acc[2][c] += w.z * f[c];
        acc[3][c] += w.w * f[c];
      }
    }
  }
  float4 inv = make_float4(1.f / fmaxf(sm.x, 1e-9f), 1.f / fmaxf(sm.y, 1e-9f),
                           1.f / fmaxf(sm.z, 1e-9f), 1.f / fmaxf(sm.w, 1e-9f));
  float iv[4] = {inv.x, inv.y, inv.z, inv.w};
  #pragma unroll
  for (int h = 0; h < 4; h++) {
    float* up = u + (((size_t)(e * 4 + h) * NN) + d) * 64 + c0;
    *(float4*)up       = make_float4(acc[h][0]*iv[h], acc[h][1]*iv[h],
                                     acc[h][2]*iv[h], acc[h][3]*iv[h]);
    *(float4*)(up + 4) = make_float4(acc[h][4]*iv[h], acc[h][5]*iv[h],
                                     acc[h][6]*iv[h], acc[h][7]*iv[h]);
  }
}

// ===== column sums of u per (e,h) =====
__global__ __launch_bounds__(256) void colsum_u_k(
    const float* __restrict__ u, float* __restrict__ usum) {
  __shared__ float lds[4][64];
  int eh = blockIdx.x >> 6;
  int chunk = blockIdx.x & 63;
  int c = threadIdx.x & 63, rg = threadIdx.x >> 6;
  const float* up = u + (size_t)eh * NN * 64;
  int n0 = chunk * 782;
  int n1 = n0 + 782; if (n1 > NN) n1 = NN;
  float s = 0.f;
  for (int n = n0 + rg; n < n1; n += 4) s += up[(size_t)n * 64 + c];
  lds[rg][c] = s;
  __syncthreads();
  if (rg == 0) {
    float t = lds[0][c] + lds[1][c] + lds[2][c] + lds[3][c];
    unsafeAtomicAdd(&usum[eh * 64 + c], t);
  }
}

__global__ __launch_bounds__(256) void mean_k(
    const float* __restrict__ usum, const float* __restrict__ Wm,
    float* __restrict__ mean) {
  int c = threadIdx.x;
  int h = c >> 6;
  float s = 0.f;
  for (int e = 0; e < 2; e++) {
    const float* us = usum + (e * 4 + h) * 64;
    const float* wp = Wm + (size_t)e * 64 * 256 + c;
    for (int k = 0; k < 64; k++) s += us[k] * wp[(size_t)k * 256];
  }
  mean[c] = s * (0.5f / NN);
}

// ===== out = 0.5*sum_e u_eh @ Wm_e[:,h*64..] - mean — MFMA =====
__global__ __launch_bounds__(256) void out_gemm_k(
    const float* __restrict__ u, const unsigned short* __restrict__ wmh,
    const unsigned short* __restrict__ wml, const float* __restrict__ mean,
    float* __restrict__ out) {
  __shared__ uint4 AsH[512], AsL[512];
  const int h = blockIdx.y;
  const int tid = threadIdx.x;
  const int row0 = blockIdx.x * 128;
  const int wv = tid >> 6, lane = tid & 63;
  const int l15 = lane & 15, lg = lane >> 4;
  f32x4 acc[2][4] = {};
  const uint4* bh4 = (const uint4*)wmh;
  const uint4* bl4 = (const uint4*)wml;
  for (int e = 0; e < 2; e++) {
    const float* Ap = u + (size_t)(e * 4 + h) * NN * 64;
    for (int k0 = 0; k0 < 64; k0 += 32) {
      {
        int r = tid & 127, half = tid >> 7;
        int rr = row0 + r; if (rr >= NN) rr = NN - 1;
        const float* ap = Ap + (size_t)rr * 64 + k0;
        #pragma unroll
        for (int i = 0; i < 2; i++) {
          int kg = half * 2 + i;
          float4 a0 = *(const float4*)(ap + kg * 8);
          float4 a1 = *(const float4*)(ap + kg * 8 + 4);
          float v[8] = {a0.x, a0.y, a0.z, a0.w, a1.x, a1.y, a1.z, a1.w};
          uint4 hh, ll;
          split_pack8(v, hh, ll);
          AsH[kg * 128 + r] = hh;
          AsL[kg * 128 + r] = ll;
        }
      }
      __syncthreads();
      short8v ah[2], al[2];
      #pragma unroll
      for (int mf = 0; mf < 2; mf++) {
        int slot = lg * 128 + wv * 32 + mf * 16 + l15;
        ah[mf] = *reinterpret_cast<const short8v*>(&AsH[slot]);
        al[mf] = *reinterpret_cast<const short8v*>(&AsL[slot]);
      }
      int kgb = e * 8 + (k0 >> 3) + lg;
      #pragma unroll
      for (int nf = 0; nf < 4; nf++) {
        int bslot = kgb * 256 + h * 64 + nf * 16 + l15;
        short8v bh = *reinterpret_cast<const short8v*>(&bh4[bslot]);
        short8v bl = *reinterpret_cast<const short8v*>(&bl4[bslot]);
        #pragma unroll
        for (int mf = 0; mf < 2; mf++) {
          acc[mf][nf] = __builtin_amdgcn_mfma_f32_16x16x32_bf16(ah[mf], bh, acc[mf][nf], 0, 0, 0);
          acc[mf][nf] = __builtin_amdgcn_mfma_f32_16x16x32_bf16(al[mf], bh, acc[mf][nf], 0, 0, 0);
          acc[mf][nf] = __builtin_amdgcn_mfma_f32_16x16x32_bf16(ah[mf], bl, acc[mf][nf], 0, 0, 0);
        }
      }
      __syncthreads();
    }
  }
  #pragma unroll
  for (int nf = 0; nf < 4; nf++) {
    int col = nf * 16 + l15;
    float mn = mean[h * 64 + col];
    #pragma unroll
    for (int mf = 0; mf < 2; mf++) {
      #pragma unroll
      for (int reg = 0; reg < 4; reg++) {
        int row = row0 + wv * 32 + mf * 16 + lg * 4 + reg;
        if (row < NN)
          out[(size_t)row * 256 + h * 64 + col] = 0.5f * acc[mf][nf][reg] - mn;
      }
    }
  }
}

// ================= host-side launch =================
extern "C" void kernel_launch(void* const* d_in, const int* in_sizes, int n_in,
                              void* d_out, int out_size, void* d_ws, size_t ws_size,
                              hipStream_t stream) {
  const float* x  = (const float*)d_in[0];
  const int* src0 = (const int*)d_in[1];
  const int* dst0 = (const int*)d_in[2];
  const int* src1 = (const int*)d_in[3];
  const int* dst1 = (const int*)d_in[4];
  const float* W1  = (const float*)d_in[5];
  const float* al1 = (const float*)d_in[6];
  const float* ar1 = (const float*)d_in[7];
  const float* b1  = (const float*)d_in[8];
  const float* W2  = (const float*)d_in[9];
  const float* al2 = (const float*)d_in[10];
  const float* ar2 = (const float*)d_in[11];
  const float* b2  = (const float*)d_in[12];
  const float* Wm  = (const float*)d_in[13];
  const float* alm = (const float*)d_in[14];
  const float* arm = (const float*)d_in[15];
  // d_in[16] = bm: cancels under per-head mean-centering
  const float* fcw = (const float*)d_in[17];
  float* out = (float*)d_out;

  float* ws = (float*)d_ws;
  float* zu     = ws;                                  // u1 fp32 12.8M / u 25.6M
  unsigned int* z2b = (unsigned int*)(ws + 12800000);  // bf16 z2, 3.2M uints
  unsigned int* xb = (unsigned int*)(ws + 25600000);   // bf16 x, 3.2M uints
  unsigned int* h2b = (unsigned int*)(ws + 32000000);  // 1.6M uints
  float* el     = ws + 33600000;   // 0.4M
  float* er     = ws + 34000000;   // 0.4M
  float* elm    = ws + 34400000;   // 0.4M
  float* erm    = ws + 34800000;   // 0.4M
  float* wl1    = ws + 35200000;
  float* wr1    = wl1 + 256;
  float* wl2    = wr1 + 256;
  float* wr2    = wl2 + 256;
  float* wlm    = wr2 + 256;
  float* wrm    = wlm + 512;
  float* usum   = wrm + 512;
  float* meanp  = usum + 512;
  int* rowptr  = (int*)(meanp + 256);          // 2*50001
  int* csr_src = rowptr + 100002;              // 2*EE
  // pre-split weights (bf16 hi/lo, frag-linear), 16B-aligned
  unsigned short* w1h = (unsigned short*)(csr_src + 2 * EE + 2);
  unsigned short* w1l = w1h + 32768;
  unsigned short* w2h = w1l + 32768;
  unsigned short* w2l = w2h + 16384;
  unsigned short* wmh = w2l + 16384;
  unsigned short* wml = wmh + 32768;
  // CSR-build temporaries (zu region free until agg_x_f)
  int* rel    = (int*)zu;                      // 2*EE ints
  int* bsum   = (int*)zu + 2 * EE;             // 2*128 ints
  int* deg    = (int*)zu + 2 * EE + 256;       // 100000 ints
  int* inc    = deg + 100000;                  // 100000 ints

  hipMemsetAsync(deg, 0, 2 * 50000 * sizeof(int), stream);
  hipMemsetAsync(usum, 0, 512 * sizeof(float), stream);
  fold_k<<<8, 256, 0, stream>>>(W1, al1, ar1, W2, al2, ar2, Wm, alm, arm,
                                wl1, wr1, wl2, wr2, wlm, wrm);
  // passA ∥ xdot ∥ wtrans (independent; xdot hides under passA's atomic stall)
  front_k<<<5008, 256, 0, stream>>>(dst0, dst1, deg, rel,
                                    x, wl1, wr1, xb, el, er,
                                    W1, W2, Wm, w1h, w1l, w2h, w2l, wmh, wml);
  scan1_k<<<dim3(98, 2), 512, 0, stream>>>(deg, inc, bsum);
  scan2_k<<<2, 128, 0, stream>>>(bsum, 98);
  scan3_k<<<dim3(196, 2), 256, 0, stream>>>(deg, inc, bsum, rowptr);
  passB_k<<<8 * SC_BPR, 256, 0, stream>>>(src0, dst0, src1, dst1,
                                          rel, rowptr, csr_src);

  // ================= layer 1 =================
  agg_x_f<<<dim3(3125, 2), 256, 0, stream>>>(rowptr, csr_src, el, er,
                                             (const uint4*)xb, zu);
  layer12_k<<<782, 256, 0, stream>>>(zu, w1h, w1l, b1, w2h, w2l, wl2, wr2,
                                     z2b, el, er);

  // ================= layer 2 =================
  agg2_f<<<1563, 256, 0, stream>>>(rowptr, csr_src, el, er, (const uint4*)z2b,
                                   b2, fcw, wlm, wrm, (uint4*)h2b, elm, erm);

  // ================= MH layer =================
  agg_mh_k<<<dim3(1563, 2), 256, 0, stream>>>(rowptr, csr_src, elm, erm,
                                              (const uint4*)h2b, zu);
  colsum_u_k<<<512, 256, 0, stream>>>(zu, usum);
  mean_k<<<1, 256, 0, stream>>>(usum, Wm, meanp);
  out_gemm_k<<<dim3(391, 4), 256, 0, stream>>>(zu, wmh, wml, meanp, out);
}